// Round 6
// baseline (44.504 us; speedup 1.0000x reference)
//
#include <hip/hip_runtime.h>

#define KK 4
#define TT 100000
#define NCLS 100
#define NN 4096
#define MARGIN_F 0.2f
#define EPS_F 1e-8f

#define NBLOCKS 2048
#define NXCD 8
#define STRIDE_K (512 * 4 * 8)   // 16384 triplet-groups per k
#define ITERS 7                  // ceil(TT / STRIDE_K)
#define NCOPY 8
#define ACC_BYTES 256
#define HB_BYTES (NN * KK * 128 * 2)   // fp16 batch, 4 MB

typedef _Float16 h2 __attribute__((ext_vector_type(2)));
struct H8 { h2 a, b, c, d; };        // 16 B = 8 halves

// fp32->fp16 convert + beta-lookup table + ws accumulator zeroing
__global__ __launch_bounds__(256) void prep(
    const float* __restrict__ src, const int* __restrict__ labels,
    const float* __restrict__ beta,
    _Float16* __restrict__ dst, float* __restrict__ bl, float* __restrict__ ws)
{
    const int i = blockIdx.x * blockDim.x + threadIdx.x;   // 0..262143
    const float4 v0 = ((const float4*)src)[i * 2];
    const float4 v1 = ((const float4*)src)[i * 2 + 1];
    H8 o;
    o.a = h2{(_Float16)v0.x, (_Float16)v0.y};
    o.b = h2{(_Float16)v0.z, (_Float16)v0.w};
    o.c = h2{(_Float16)v1.x, (_Float16)v1.y};
    o.d = h2{(_Float16)v1.z, (_Float16)v1.w};
    ((H8*)dst)[i] = o;

    if (i < KK * NN) {                      // bl[k][n] = beta[k][labels[n]]
        const int n = i >> 2, k = i & 3;
        bl[k * NN + n] = beta[k * NCLS + labels[n]];
    }
    if (i < NCOPY * 8) ws[i] = 0.f;
}

__device__ __forceinline__ void tri_compute(
    const H8& a0, const H8& a1, const H8& p0, const H8& p1,
    const H8& n0, const H8& n1, const float b, const int s,
    float& lt, float& lc)
{
    float sap = 0.f, san = 0.f;
    h2 d;
    d = a0.a - p0.a; sap = __builtin_amdgcn_fdot2(d, d, sap, false);
    d = a0.b - p0.b; sap = __builtin_amdgcn_fdot2(d, d, sap, false);
    d = a0.c - p0.c; sap = __builtin_amdgcn_fdot2(d, d, sap, false);
    d = a0.d - p0.d; sap = __builtin_amdgcn_fdot2(d, d, sap, false);
    d = a1.a - p1.a; sap = __builtin_amdgcn_fdot2(d, d, sap, false);
    d = a1.b - p1.b; sap = __builtin_amdgcn_fdot2(d, d, sap, false);
    d = a1.c - p1.c; sap = __builtin_amdgcn_fdot2(d, d, sap, false);
    d = a1.d - p1.d; sap = __builtin_amdgcn_fdot2(d, d, sap, false);

    d = a0.a - n0.a; san = __builtin_amdgcn_fdot2(d, d, san, false);
    d = a0.b - n0.b; san = __builtin_amdgcn_fdot2(d, d, san, false);
    d = a0.c - n0.c; san = __builtin_amdgcn_fdot2(d, d, san, false);
    d = a0.d - n0.d; san = __builtin_amdgcn_fdot2(d, d, san, false);
    d = a1.a - n1.a; san = __builtin_amdgcn_fdot2(d, d, san, false);
    d = a1.b - n1.b; san = __builtin_amdgcn_fdot2(d, d, san, false);
    d = a1.c - n1.c; san = __builtin_amdgcn_fdot2(d, d, san, false);
    d = a1.d - n1.d; san = __builtin_amdgcn_fdot2(d, d, san, false);

    #pragma unroll
    for (int o = 4; o; o >>= 1) {
        sap += __shfl_xor(sap, o);
        san += __shfl_xor(san, o);
    }

    if (s == 0) {
        const float d_ap = sqrtf(sap + EPS_F);
        const float d_an = sqrtf(san + EPS_F);
        const float pl = fmaxf(d_ap - b + MARGIN_F, 0.f);
        const float nl = fmaxf(b - d_an + MARGIN_F, 0.f);
        lt += pl + nl;
        lc += (pl > 0.f || nl > 0.f) ? 1.f : 0.f;
    }
}

// ws layout: ws[c*8 + j], j<4: totals, j>=4: counts
__global__ __launch_bounds__(256, 4) void margin_main(
    const _Float16* __restrict__ hb,
    const int* __restrict__ triplets,
    const float* __restrict__ bl,
    float* __restrict__ ws)
{
    __shared__ float s_red[8];
    const int tid  = threadIdx.x;
    const int lane = tid & 63;
    const int wave = tid >> 6;
    const int g    = lane >> 3;       // group in wave (8 lanes/triplet)
    const int s    = lane & 7;        // sub-lane in group

    // XCD-pinned k: blocks round-robin over 8 XCDs; 2 XCDs own each k.
    const int xcd      = blockIdx.x & (NXCD - 1);
    const int k        = xcd >> 1;                               // 0..3
    const int blk_in_k = ((xcd & 1) << 8) | (blockIdx.x >> 3);   // 0..511

    const int g0 = blk_in_k * 32 + wave * 8 + g;

    const int* __restrict__ trip_k = triplets + k * (TT * 3);
    const float* __restrict__ bl_k = bl + k * NN;
    const H8* __restrict__ hb8 = (const H8*)hb;

    // ---- phase 1: preload ALL triplet indices (7 iters x 3), clamped ----
    int ja[ITERS], jp[ITERS], jn[ITERS];
    #pragma unroll
    for (int j = 0; j < ITERS; ++j) {
        const int t  = g0 + j * STRIDE_K;
        const int tt = (j < ITERS - 1 || t < TT) ? t : 0;   // folds for j<6
        const int* tp = trip_k + tt * 3;
        ja[j] = tp[0]; jp[j] = tp[1]; jn[j] = tp[2];
    }
    // ---- phase 2: beta gathers, all issued together ----
    float jb[ITERS];
    #pragma unroll
    for (int j = 0; j < ITERS; ++j) jb[j] = bl_k[ja[j]];

    // ---- phase 3: row gathers + compute, fully unrolled (independent) ----
    float lt = 0.f, lc = 0.f;
    #pragma unroll
    for (int j = 0; j < ITERS; ++j) {
        const int t = g0 + j * STRIDE_K;
        if (j < ITERS - 1 || t < TT) {      // compile-time true for j<6
            const H8* a = hb8 + (((ja[j] << 2) + k) << 4);
            const H8* p = hb8 + (((jp[j] << 2) + k) << 4);
            const H8* n = hb8 + (((jn[j] << 2) + k) << 4);
            const H8 r0 = a[s], r1 = a[8 + s];
            const H8 q0 = p[s], q1 = p[8 + s];
            const H8 u0 = n[s], u1 = n[8 + s];
            tri_compute(r0, r1, q0, q1, u0, u1, jb[j], s, lt, lc);
        }
    }

    // combine the 8 s==0 lanes of this wave (others hold zeros)
    #pragma unroll
    for (int o = 8; o <= 32; o <<= 1) {
        lt += __shfl_xor(lt, o);
        lc += __shfl_xor(lc, o);
    }
    if (lane == 0) { s_red[wave] = lt; s_red[4 + wave] = lc; }
    __syncthreads();

    if (tid == 0) {
        const float tot = s_red[0] + s_red[1] + s_red[2] + s_red[3];
        const float cnt = s_red[4] + s_red[5] + s_red[6] + s_red[7];
        const int c = (blockIdx.x >> 3) & (NCOPY - 1);
        atomicAdd(&ws[c * 8 + k], tot);
        atomicAdd(&ws[c * 8 + 4 + k], cnt);
    }
}

__global__ void margin_final(const float* __restrict__ ws, float* __restrict__ out) {
    if (threadIdx.x == 0 && blockIdx.x == 0) {
        float acc = 0.f;
        #pragma unroll
        for (int k = 0; k < KK; ++k) {
            float tot = 0.f, cnt = 0.f;
            #pragma unroll
            for (int c = 0; c < NCOPY; ++c) {
                tot += ws[c * 8 + k];
                cnt += ws[c * 8 + 4 + k];
            }
            const float lk = (cnt == 0.f) ? tot : tot / fmaxf(cnt, 1.f);
            acc += lk;
        }
        out[0] = acc / (float)KK;
    }
}

extern "C" void kernel_launch(void* const* d_in, const int* in_sizes, int n_in,
                              void* d_out, int out_size, void* d_ws, size_t ws_size,
                              hipStream_t stream) {
    const float* batch    = (const float*)d_in[0];
    const int*   labels   = (const int*)d_in[1];
    const int*   triplets = (const int*)d_in[2];
    const float* beta     = (const float*)d_in[3];

    float*     ws = (float*)d_ws;
    _Float16*  hb = (_Float16*)((char*)d_ws + ACC_BYTES);
    float*     bl = (float*)((char*)d_ws + ACC_BYTES + HB_BYTES);

    prep<<<1024, 256, 0, stream>>>(batch, labels, beta, hb, bl, ws);
    margin_main<<<NBLOCKS, 256, 0, stream>>>(hb, triplets, bl, ws);
    margin_final<<<1, 64, 0, stream>>>(ws, (float*)d_out);
}

// Round 8
// 42.794 us; speedup vs baseline: 1.0400x; 1.0400x over previous
//
#include <hip/hip_runtime.h>

#define KK 4
#define TT 100000
#define NCLS 100
#define NN 4096
#define MARGIN_F 0.2f
#define EPS_F 1e-8f

#define NBLOCKS 2048
#define NXCD 8
#define STRIDE_K (512 * 4 * 8)   // 16384 triplet-groups per k
#define ITERS 7                  // ceil(TT / STRIDE_K); j=6 partial
#define NCOPY 8
#define ACC_BYTES 256
#define HB_BYTES (NN * KK * 128 * 2)   // fp16 batch, 4 MB

typedef _Float16 h2 __attribute__((ext_vector_type(2)));
struct H8 { h2 a, b, c, d; };        // 16 B = 8 halves

// fp32->fp16 convert + beta-lookup table + ws accumulator zeroing
__global__ __launch_bounds__(256) void prep(
    const float* __restrict__ src, const int* __restrict__ labels,
    const float* __restrict__ beta,
    _Float16* __restrict__ dst, float* __restrict__ bl, float* __restrict__ ws)
{
    const int i = blockIdx.x * blockDim.x + threadIdx.x;   // 0..262143
    const float4 v0 = ((const float4*)src)[i * 2];
    const float4 v1 = ((const float4*)src)[i * 2 + 1];
    H8 o;
    o.a = h2{(_Float16)v0.x, (_Float16)v0.y};
    o.b = h2{(_Float16)v0.z, (_Float16)v0.w};
    o.c = h2{(_Float16)v1.x, (_Float16)v1.y};
    o.d = h2{(_Float16)v1.z, (_Float16)v1.w};
    ((H8*)dst)[i] = o;

    if (i < KK * NN) {                      // bl[k][n] = beta[k][labels[n]]
        const int n = i >> 2, k = i & 3;
        bl[k * NN + n] = beta[k * NCLS + labels[n]];
    }
    if (i < NCOPY * 8) ws[i] = 0.f;
}

// xor1 / xor2 within quad via DPP quad_perm (VALU pipe, no DS)
template <int CTRL>
__device__ __forceinline__ float dpp_xor_add(float x) {
    const int xi = __builtin_bit_cast(int, x);
    const int yi = __builtin_amdgcn_update_dpp(0, xi, CTRL, 0xF, 0xF, true);
    return x + __builtin_bit_cast(float, yi);
}
// xor4 via single ds_swizzle level
__device__ __forceinline__ float swz_xor4_add(float x) {
    const int xi = __builtin_bit_cast(int, x);
    const int yi = __builtin_amdgcn_ds_swizzle(xi, 0x101F);
    return x + __builtin_bit_cast(float, yi);
}

// ws layout: ws[c*8 + j], j<4: totals, j>=4: counts
__global__ __launch_bounds__(256, 4) void margin_main(
    const _Float16* __restrict__ hb,
    const int* __restrict__ triplets,
    const float* __restrict__ bl,
    float* __restrict__ ws)
{
    __shared__ float s_red[8];
    const int tid  = threadIdx.x;
    const int lane = tid & 63;
    const int wave = tid >> 6;
    const int g    = lane >> 3;       // group in wave (8 lanes/triplet)
    const int s    = lane & 7;        // sub-lane in group

    // XCD-pinned k: blocks round-robin over 8 XCDs; 2 XCDs own each k.
    const int xcd      = blockIdx.x & (NXCD - 1);
    const int k        = xcd >> 1;                               // 0..3
    const int blk_in_k = ((xcd & 1) << 8) | (blockIdx.x >> 3);   // 0..511

    const int g0 = blk_in_k * 32 + wave * 8 + g;

    const int* __restrict__ trip_k = triplets + k * (TT * 3);
    const float* __restrict__ bl_k = bl + k * NN;
    const H8* __restrict__ hb8 = (const H8*)hb;

    // ---- phase 1: preload ALL triplet indices (clamped), fenced ----
    int ja[ITERS], jp[ITERS], jn[ITERS];
    #pragma unroll
    for (int j = 0; j < ITERS; ++j) {
        const int t  = g0 + j * STRIDE_K;
        const int tt = (j < ITERS - 1 || t < TT) ? t : 0;
        const int* tp = trip_k + tt * 3;
        ja[j] = tp[0]; jp[j] = tp[1]; jn[j] = tp[2];
    }
    __builtin_amdgcn_sched_barrier(0);

    // ---- phase 2: beta gathers, all issued together ----
    float jb[ITERS];
    #pragma unroll
    for (int j = 0; j < ITERS; ++j) jb[j] = bl_k[ja[j]];
    __builtin_amdgcn_sched_barrier(0);

    // ---- phase 3: 2-ahead software-pipelined row gathers + compute ----
    H8 R[3][6];   // 3 in-flight triplets x {a0,a1,p0,p1,n0,n1}; statically indexed

    #define ISSUE(SLOT, J)                                                   \
        {                                                                    \
            const H8* a_ = hb8 + (((ja[(J)] << 2) + k) << 4);                \
            const H8* p_ = hb8 + (((jp[(J)] << 2) + k) << 4);                \
            const H8* n_ = hb8 + (((jn[(J)] << 2) + k) << 4);                \
            R[(SLOT)][0] = a_[s];  R[(SLOT)][1] = a_[8 + s];                 \
            R[(SLOT)][2] = p_[s];  R[(SLOT)][3] = p_[8 + s];                 \
            R[(SLOT)][4] = n_[s];  R[(SLOT)][5] = n_[8 + s];                 \
        }

    ISSUE(0, 0)
    ISSUE(1, 1)
    __builtin_amdgcn_sched_barrier(0);

    float lt = 0.f, lc = 0.f;

    #pragma unroll
    for (int j = 0; j < ITERS; ++j) {
        if (j + 2 < ITERS) {
            ISSUE((j + 2) % 3, j + 2)
            __builtin_amdgcn_sched_barrier(0);
        }
        const int slot = j % 3;   // constant after unroll
        const H8 a0 = R[slot][0], a1 = R[slot][1];
        const H8 p0 = R[slot][2], p1 = R[slot][3];
        const H8 n0 = R[slot][4], n1 = R[slot][5];

        float sap = 0.f, san = 0.f;
        h2 d;
        d = a0.a - p0.a; sap = __builtin_amdgcn_fdot2(d, d, sap, false);
        d = a0.b - p0.b; sap = __builtin_amdgcn_fdot2(d, d, sap, false);
        d = a0.c - p0.c; sap = __builtin_amdgcn_fdot2(d, d, sap, false);
        d = a0.d - p0.d; sap = __builtin_amdgcn_fdot2(d, d, sap, false);
        d = a1.a - p1.a; sap = __builtin_amdgcn_fdot2(d, d, sap, false);
        d = a1.b - p1.b; sap = __builtin_amdgcn_fdot2(d, d, sap, false);
        d = a1.c - p1.c; sap = __builtin_amdgcn_fdot2(d, d, sap, false);
        d = a1.d - p1.d; sap = __builtin_amdgcn_fdot2(d, d, sap, false);

        d = a0.a - n0.a; san = __builtin_amdgcn_fdot2(d, d, san, false);
        d = a0.b - n0.b; san = __builtin_amdgcn_fdot2(d, d, san, false);
        d = a0.c - n0.c; san = __builtin_amdgcn_fdot2(d, d, san, false);
        d = a0.d - n0.d; san = __builtin_amdgcn_fdot2(d, d, san, false);
        d = a1.a - n1.a; san = __builtin_amdgcn_fdot2(d, d, san, false);
        d = a1.b - n1.b; san = __builtin_amdgcn_fdot2(d, d, san, false);
        d = a1.c - n1.c; san = __builtin_amdgcn_fdot2(d, d, san, false);
        d = a1.d - n1.d; san = __builtin_amdgcn_fdot2(d, d, san, false);

        // 8-lane reduce: xor1, xor2 on VALU (DPP); xor4 one DS level
        sap = dpp_xor_add<0xB1>(sap);   // quad_perm [1,0,3,2]
        san = dpp_xor_add<0xB1>(san);
        sap = dpp_xor_add<0x4E>(sap);   // quad_perm [2,3,0,1]
        san = dpp_xor_add<0x4E>(san);
        sap = swz_xor4_add(sap);
        san = swz_xor4_add(san);

        // tail on all lanes, masked accumulate (no branch)
        const int t = g0 + j * STRIDE_K;
        const bool act = (s == 0) && (t < TT);
        const float d_ap = sqrtf(sap + EPS_F);
        const float d_an = sqrtf(san + EPS_F);
        const float pl = fmaxf(d_ap - jb[j] + MARGIN_F, 0.f);
        const float nl = fmaxf(jb[j] - d_an + MARGIN_F, 0.f);
        lt += act ? (pl + nl) : 0.f;
        lc += (act && (pl > 0.f || nl > 0.f)) ? 1.f : 0.f;
    }
    #undef ISSUE

    // combine the 8 s==0 lanes of this wave (others hold zeros)
    #pragma unroll
    for (int o = 8; o <= 32; o <<= 1) {
        lt += __shfl_xor(lt, o);
        lc += __shfl_xor(lc, o);
    }
    if (lane == 0) { s_red[wave] = lt; s_red[4 + wave] = lc; }
    __syncthreads();

    if (tid == 0) {
        const float tot = s_red[0] + s_red[1] + s_red[2] + s_red[3];
        const float cnt = s_red[4] + s_red[5] + s_red[6] + s_red[7];
        const int c = (blockIdx.x >> 3) & (NCOPY - 1);
        atomicAdd(&ws[c * 8 + k], tot);
        atomicAdd(&ws[c * 8 + 4 + k], cnt);
    }
}

__global__ void margin_final(const float* __restrict__ ws, float* __restrict__ out) {
    if (threadIdx.x == 0 && blockIdx.x == 0) {
        float acc = 0.f;
        #pragma unroll
        for (int k = 0; k < KK; ++k) {
            float tot = 0.f, cnt = 0.f;
            #pragma unroll
            for (int c = 0; c < NCOPY; ++c) {
                tot += ws[c * 8 + k];
                cnt += ws[c * 8 + 4 + k];
            }
            const float lk = (cnt == 0.f) ? tot : tot / fmaxf(cnt, 1.f);
            acc += lk;
        }
        out[0] = acc / (float)KK;
    }
}

extern "C" void kernel_launch(void* const* d_in, const int* in_sizes, int n_in,
                              void* d_out, int out_size, void* d_ws, size_t ws_size,
                              hipStream_t stream) {
    const float* batch    = (const float*)d_in[0];
    const int*   labels   = (const int*)d_in[1];
    const int*   triplets = (const int*)d_in[2];
    const float* beta     = (const float*)d_in[3];

    float*     ws = (float*)d_ws;
    _Float16*  hb = (_Float16*)((char*)d_ws + ACC_BYTES);
    float*     bl = (float*)((char*)d_ws + ACC_BYTES + HB_BYTES);

    prep<<<1024, 256, 0, stream>>>(batch, labels, beta, hb, bl, ws);
    margin_main<<<NBLOCKS, 256, 0, stream>>>(hb, triplets, bl, ws);
    margin_final<<<1, 64, 0, stream>>>(ws, (float*)d_out);
}